// Round 4
// baseline (460.117 us; speedup 1.0000x reference)
//
#include <hip/hip_runtime.h>
#include <math.h>

// GHM-C loss, single fused kernel + 192B memset.
// Grid-stride over pred treating every element as non-target (s = p):
//   bce = softplus(p); nested sums S_k = sum bce over {p >= T_k},
//   counts C_k = #{p >= T_k}, T_k = logit(k/10), all PER-LANE (no ballots —
//   R3 showed ballot/popcount histogramming stalls the wave on VALU->SALU
//   hazards: 309us, VALUBusy 14%). First N/256 blocks' threads additionally
// correct their target element (replace s=p contribution with s=-p).
// Block partials -> device-scope atomics into 19 global accumulators
// (counts as int = exact); ticket elects last block to finalize.
//
// d_ws layout: [0..39] float gS[10]; [64..99] int gC[9]; [128..131] uint ticket.

#define BLK 256
#define GRID 2048

typedef float v4f __attribute__((ext_vector_type(4)));

// logit(k/10), k=1..9
__device__ __constant__ float kT[9] = {
    -2.1972246f, -1.3862944f, -0.84729786f, -0.40546511f, 0.0f,
    0.40546511f, 0.84729786f, 1.3862944f, 2.1972246f};

__device__ __forceinline__ void wave_red(float& v) {
#pragma unroll
    for (int off = 32; off > 0; off >>= 1) v += __shfl_down(v, off, 64);
}
__device__ __forceinline__ void wave_red(int& v) {
#pragma unroll
    for (int off = 32; off > 0; off >>= 1) v += __shfl_down(v, off, 64);
}

__device__ __forceinline__ void upd(float x, float (&S)[10], int (&cnt)[9]) {
    float en = __expf(-fabsf(x));
    float bce = fmaxf(x, 0.0f) + __logf(1.0f + en);  // softplus(x), stable
    S[0] += bce;
#pragma unroll
    for (int q = 0; q < 9; ++q) {
        bool b = (x >= kT[q]);
        S[q + 1] += b ? bce : 0.0f;  // v_cmp + v_cndmask + v_add
        cnt[q] += b ? 1 : 0;         // carry-add off vcc
    }
}

// Target element with logit p: remove the s=p contribution added by the
// streaming loop, add the true s=-p contribution.
__device__ __forceinline__ void upd_corr(float p, float (&S)[10], int (&cnt)[9]) {
    float en = __expf(-fabsf(p));
    float l1p = __logf(1.0f + en);
    float bf = fmaxf(p, 0.0f) + l1p;   // false contribution (remove)
    float bt = fmaxf(-p, 0.0f) + l1p;  // true contribution (add)
    S[0] += bt - bf;
#pragma unroll
    for (int q = 0; q < 9; ++q) {
        bool btq = (-p >= kT[q]);
        bool bfq = (p >= kT[q]);
        S[q + 1] += (btq ? bt : 0.0f) - (bfq ? bf : 0.0f);
        cnt[q] += (btq ? 1 : 0) - (bfq ? 1 : 0);
    }
}

__global__ __launch_bounds__(BLK, 8) void ghmc_fused(
    const float* __restrict__ pred, const int* __restrict__ target,
    float* __restrict__ gS, int* __restrict__ gC, unsigned* __restrict__ gT,
    float* __restrict__ out, unsigned total4, unsigned totalNC, int N, int C) {
    float S[10];
    int cnt[9];
#pragma unroll
    for (int i = 0; i < 10; ++i) S[i] = 0.0f;
#pragma unroll
    for (int i = 0; i < 9; ++i) cnt[i] = 0;

    unsigned tid = blockIdx.x * blockDim.x + threadIdx.x;
    unsigned stride = gridDim.x * blockDim.x;
    const v4f* p4 = (const v4f*)pred;

    // 2-wide unrolled grid-stride: two independent dwordx4 loads in flight
    unsigned v = tid;
    for (; v + stride < total4; v += 2u * stride) {
        v4f a = p4[v];
        v4f b = p4[v + stride];
        upd(a[0], S, cnt);
        upd(a[1], S, cnt);
        upd(a[2], S, cnt);
        upd(a[3], S, cnt);
        upd(b[0], S, cnt);
        upd(b[1], S, cnt);
        upd(b[2], S, cnt);
        upd(b[3], S, cnt);
    }
    for (; v < total4; v += stride) {
        v4f a = p4[v];
        upd(a[0], S, cnt);
        upd(a[1], S, cnt);
        upd(a[2], S, cnt);
        upd(a[3], S, cnt);
    }

    // tail (NC % 4 != 0): global thread 0 only
    if (tid == 0) {
        for (unsigned e = total4 << 2; e < totalNC; ++e) upd(pred[e], S, cnt);
    }

    // per-row target correction; each row handled exactly once
    int row = (int)tid;
    if (row < N) {
        int t = target[row];
        float p = pred[(unsigned)row * (unsigned)C + (unsigned)t];
        upd_corr(p, S, cnt);
    }

    // block reduction
#pragma unroll
    for (int i = 0; i < 10; ++i) wave_red(S[i]);
#pragma unroll
    for (int i = 0; i < 9; ++i) wave_red(cnt[i]);

    __shared__ float sS[BLK / 64][10];
    __shared__ int sC[BLK / 64][9];
    int wid = threadIdx.x >> 6;
    int lane = threadIdx.x & 63;
    if (lane == 0) {
#pragma unroll
        for (int i = 0; i < 10; ++i) sS[wid][i] = S[i];
#pragma unroll
        for (int i = 0; i < 9; ++i) sC[wid][i] = cnt[i];
    }
    __syncthreads();

    if (threadIdx.x == 0) {
        const int nw = BLK / 64;
#pragma unroll
        for (int i = 0; i < 10; ++i) {
            float a = 0.0f;
            for (int w = 0; w < nw; ++w) a += sS[w][i];
            atomicAdd(&gS[i], a);
        }
#pragma unroll
        for (int i = 0; i < 9; ++i) {
            int a = 0;
            for (int w = 0; w < nw; ++w) a += sC[w][i];
            atomicAdd(&gC[i], a);
        }
        __threadfence();
        unsigned old = atomicAdd(gT, 1u);
        if (old == gridDim.x - 1u) {
            __threadfence();
            float Sv[11], Cv[11];
            for (int i = 0; i < 10; ++i) Sv[i] = atomicAdd(&gS[i], 0.0f);
            Sv[10] = 0.0f;
            Cv[0] = (float)totalNC;
            for (int i = 1; i < 10; ++i) Cv[i] = (float)atomicAdd(&gC[i - 1], 0);
            Cv[10] = 0.0f;

            int nonempty = 0;
            for (int b = 0; b < 10; ++b)
                if (Cv[b] - Cv[b + 1] > 0.5f) nonempty++;
            float n = fmaxf((float)nonempty, 1.0f);

            float loss = 0.0f;
            for (int b = 0; b < 10; ++b) {
                float c = Cv[b] - Cv[b + 1];
                if (c > 0.5f) loss += (Sv[b] - Sv[b + 1]) / (c * n);
            }
            out[0] = loss;  // LOSS_WEIGHT = 1.0
        }
    }
}

extern "C" void kernel_launch(void* const* d_in, const int* in_sizes, int n_in,
                              void* d_out, int out_size, void* d_ws, size_t ws_size,
                              hipStream_t stream) {
    const float* pred = (const float*)d_in[0];
    const int* target = (const int*)d_in[1];
    int NC = in_sizes[0];
    int N = in_sizes[1];
    int C = NC / N;
    unsigned total4 = (unsigned)(NC / 4);

    float* gS = (float*)d_ws;
    int* gC = (int*)((char*)d_ws + 64);
    unsigned* gT = (unsigned*)((char*)d_ws + 128);

    // zero the 19 accumulators + ticket (graph-legal memset node)
    hipMemsetAsync(d_ws, 0, 192, stream);

    // GRID*BLK = 524288 >= N required for the per-row correction
    ghmc_fused<<<GRID, BLK, 0, stream>>>(pred, target, gS, gC, gT,
                                         (float*)d_out, total4, (unsigned)NC,
                                         N, C);
}

// Round 5
// 200.997 us; speedup vs baseline: 2.2892x; 2.2892x over previous
//
#include <hip/hip_runtime.h>
#include <math.h>

// GHM-C loss, two-pass (NO contended atomics — R3/R4 showed a grid-wide
// atomic funnel onto 3 cache lines costs ~250us of serialized tail on
// 8-XCD MI355X; per-block disjoint slots + tiny pass2 is the right shape).
//
// Pass 1 (2048 x 256): grid-stride over pred as float4, every element treated
// as non-target (s = p): bce = softplus(p); nested accumulators
//   S_k = sum bce over {p >= T_k}, C_k = #{p >= T_k}, T_k = logit(k/10),
// per-lane cmp+cndmask+add+addc (no ballots — R3 showed VALU->SALU hazard
// stall). Threads with tid < N additionally correct their row's target
// element (replace s=p contribution with s=-p). Block partials (19 floats)
// -> disjoint d_ws slots via plain stores.
// Pass 2 (1 x 256): reduce 2048x19 partials, difference nested sums into
// per-bin values, finalize loss.

#define BLK 256
#define GRID 2048

typedef float v4f __attribute__((ext_vector_type(4)));

// logit(k/10), k=1..9
__device__ __constant__ float kT[9] = {
    -2.1972246f, -1.3862944f, -0.84729786f, -0.40546511f, 0.0f,
    0.40546511f, 0.84729786f, 1.3862944f, 2.1972246f};

__device__ __forceinline__ void wave_red(float& v) {
#pragma unroll
    for (int off = 32; off > 0; off >>= 1) v += __shfl_down(v, off, 64);
}
__device__ __forceinline__ void wave_red(int& v) {
#pragma unroll
    for (int off = 32; off > 0; off >>= 1) v += __shfl_down(v, off, 64);
}

__device__ __forceinline__ void upd(float x, float (&S)[10], int (&cnt)[9]) {
    float en = __expf(-fabsf(x));
    float bce = fmaxf(x, 0.0f) + __logf(1.0f + en);  // softplus(x), stable
    S[0] += bce;
#pragma unroll
    for (int q = 0; q < 9; ++q) {
        bool b = (x >= kT[q]);
        S[q + 1] += b ? bce : 0.0f;  // v_cmp + v_cndmask + v_add
        cnt[q] += b ? 1 : 0;         // carry-add off vcc
    }
}

// Target element with logit p: remove the s=p contribution added by the
// streaming loop, add the true s=-p contribution.
__device__ __forceinline__ void upd_corr(float p, float (&S)[10], int (&cnt)[9]) {
    float en = __expf(-fabsf(p));
    float l1p = __logf(1.0f + en);
    float bf = fmaxf(p, 0.0f) + l1p;   // false contribution (remove)
    float bt = fmaxf(-p, 0.0f) + l1p;  // true contribution (add)
    S[0] += bt - bf;
#pragma unroll
    for (int q = 0; q < 9; ++q) {
        bool btq = (-p >= kT[q]);
        bool bfq = (p >= kT[q]);
        S[q + 1] += (btq ? bt : 0.0f) - (bfq ? bf : 0.0f);
        cnt[q] += (btq ? 1 : 0) - (bfq ? 1 : 0);
    }
}

__global__ __launch_bounds__(BLK, 8) void ghmc_pass1(
    const float* __restrict__ pred, const int* __restrict__ target,
    float* __restrict__ blk, unsigned total4, unsigned totalNC, int N, int C) {
    float S[10];
    int cnt[9];
#pragma unroll
    for (int i = 0; i < 10; ++i) S[i] = 0.0f;
#pragma unroll
    for (int i = 0; i < 9; ++i) cnt[i] = 0;

    unsigned tid = blockIdx.x * blockDim.x + threadIdx.x;
    unsigned stride = gridDim.x * blockDim.x;
    const v4f* p4 = (const v4f*)pred;

    // 2-wide unrolled grid-stride: two independent dwordx4 loads in flight
    unsigned v = tid;
    for (; v + stride < total4; v += 2u * stride) {
        v4f a = p4[v];
        v4f b = p4[v + stride];
        upd(a[0], S, cnt);
        upd(a[1], S, cnt);
        upd(a[2], S, cnt);
        upd(a[3], S, cnt);
        upd(b[0], S, cnt);
        upd(b[1], S, cnt);
        upd(b[2], S, cnt);
        upd(b[3], S, cnt);
    }
    for (; v < total4; v += stride) {
        v4f a = p4[v];
        upd(a[0], S, cnt);
        upd(a[1], S, cnt);
        upd(a[2], S, cnt);
        upd(a[3], S, cnt);
    }

    // tail (NC % 4 != 0): global thread 0 only
    if (tid == 0) {
        for (unsigned e = total4 << 2; e < totalNC; ++e) upd(pred[e], S, cnt);
    }

    // per-row target correction; each row handled exactly once
    int row = (int)tid;
    if (row < N) {
        int t = target[row];
        float p = pred[(unsigned)row * (unsigned)C + (unsigned)t];
        upd_corr(p, S, cnt);
    }

    // block reduction
#pragma unroll
    for (int i = 0; i < 10; ++i) wave_red(S[i]);
#pragma unroll
    for (int i = 0; i < 9; ++i) wave_red(cnt[i]);

    __shared__ float sS[BLK / 64][10];
    __shared__ int sC[BLK / 64][9];
    int wid = threadIdx.x >> 6;
    int lane = threadIdx.x & 63;
    if (lane == 0) {
#pragma unroll
        for (int i = 0; i < 10; ++i) sS[wid][i] = S[i];
#pragma unroll
        for (int i = 0; i < 9; ++i) sC[wid][i] = cnt[i];
    }
    __syncthreads();
    if (threadIdx.x == 0) {
        const int nw = BLK / 64;
        float o[19];
#pragma unroll
        for (int i = 0; i < 10; ++i) {
            float a = 0.0f;
            for (int w = 0; w < nw; ++w) a += sS[w][i];
            o[i] = a;
        }
#pragma unroll
        for (int i = 0; i < 9; ++i) {
            int a = 0;
            for (int w = 0; w < nw; ++w) a += sC[w][i];
            o[10 + i] = (float)a;  // counts <= 524288, exact in fp32
        }
        float* dst = blk + (unsigned)blockIdx.x * 20u;  // 20-stride: aligned slots
#pragma unroll
        for (int i = 0; i < 19; ++i) dst[i] = o[i];
    }
}

__global__ __launch_bounds__(256) void ghmc_pass2(
    const float* __restrict__ blk, float* __restrict__ out, int nblocks,
    float totalNC) {
    float P[19];
#pragma unroll
    for (int i = 0; i < 19; ++i) P[i] = 0.0f;

    for (int b = threadIdx.x; b < nblocks; b += 256) {
        const float* src = blk + (unsigned)b * 20u;
#pragma unroll
        for (int i = 0; i < 19; ++i) P[i] += src[i];
    }
#pragma unroll
    for (int i = 0; i < 19; ++i) wave_red(P[i]);

    __shared__ float sP[4][19];
    int wid = threadIdx.x >> 6;
    int lane = threadIdx.x & 63;
    if (lane == 0) {
#pragma unroll
        for (int i = 0; i < 19; ++i) sP[wid][i] = P[i];
    }
    __syncthreads();
    if (threadIdx.x == 0) {
        float Sv[11], Cv[11];
        for (int i = 0; i < 19; ++i) {
            float a = 0.0f;
            for (int w = 0; w < 4; ++w) a += sP[w][i];
            P[i] = a;
        }
        for (int i = 0; i < 10; ++i) Sv[i] = P[i];
        Sv[10] = 0.0f;
        Cv[0] = totalNC;
        for (int i = 1; i < 10; ++i) Cv[i] = P[9 + i];
        Cv[10] = 0.0f;

        int nonempty = 0;
        for (int b = 0; b < 10; ++b)
            if (Cv[b] - Cv[b + 1] > 0.5f) nonempty++;
        float n = fmaxf((float)nonempty, 1.0f);

        float loss = 0.0f;
        for (int b = 0; b < 10; ++b) {
            float c = Cv[b] - Cv[b + 1];
            if (c > 0.5f) loss += (Sv[b] - Sv[b + 1]) / (c * n);
        }
        out[0] = loss;  // LOSS_WEIGHT = 1.0
    }
}

extern "C" void kernel_launch(void* const* d_in, const int* in_sizes, int n_in,
                              void* d_out, int out_size, void* d_ws, size_t ws_size,
                              hipStream_t stream) {
    const float* pred = (const float*)d_in[0];
    const int* target = (const int*)d_in[1];
    int NC = in_sizes[0];
    int N = in_sizes[1];
    int C = NC / N;
    unsigned total4 = (unsigned)(NC / 4);

    int blocks = GRID;
    size_t per_block = 20 * sizeof(float);
    if (ws_size < (size_t)blocks * per_block) {
        size_t maxb = ws_size / per_block;
        blocks = (int)(maxb > 0 ? maxb : 1);
    }
    // per-row correction requires blocks*BLK >= N (2048*256 = 524288 >= 32768)

    float* blkbuf = (float*)d_ws;

    ghmc_pass1<<<blocks, BLK, 0, stream>>>(pred, target, blkbuf, total4,
                                           (unsigned)NC, N, C);
    ghmc_pass2<<<1, 256, 0, stream>>>(blkbuf, (float*)d_out, blocks, (float)NC);
}